// Round 3
// baseline (5781.177 us; speedup 1.0000x reference)
//
#include <hip/hip_runtime.h>
#include <hip/hip_bf16.h>

// Problem constants (from reference): N=100000 nodes, E=1600000 edges, D=128.
#define NDIM 128

// Build concatenated transposed weights: Wcat[k][j] for k in [0,256):
//   k <  128 : W_l[j][k]      (applied to mean-aggregated features)
//   k >= 128 : W_r[j][k-128]  (applied to self features)
__global__ __launch_bounds__(256) void build_wcat_kernel(
    const float* __restrict__ W1l, const float* __restrict__ W1r,
    const float* __restrict__ W2l, const float* __restrict__ W2r,
    float* __restrict__ wc1, float* __restrict__ wc2)
{
    int idx = blockIdx.x * 256 + threadIdx.x;
    if (idx >= 256 * 128) return;
    int k = idx >> 7;
    int j = idx & 127;
    float v1, v2;
    if (k < 128) {
        v1 = W1l[j * 128 + k];
        v2 = W2l[j * 128 + k];
    } else {
        v1 = W1r[j * 128 + (k - 128)];
        v2 = W2r[j * 128 + (k - 128)];
    }
    wc1[idx] = v1;
    wc2[idx] = v2;
}

// Scatter-add mean-aggregation numerator: for each edge e, agg[dst[e]] += feat[src[e]].
// One 32-lane half-wave per edge; each lane handles a float4 (32*4 = 128 dims).
// Optionally accumulates degree (first layer only).
__global__ __launch_bounds__(256) void scatter_kernel(
    const float* __restrict__ feat, const int* __restrict__ ei,
    float* __restrict__ agg, float* __restrict__ deg, int E)
{
    int g = (blockIdx.x * 256 + threadIdx.x) >> 5;   // edge id
    int lane = threadIdx.x & 31;
    if (g >= E) return;
    int src = ei[g];          // edge_index[0][e]
    int dst = ei[E + g];      // edge_index[1][e]
    float4 v = reinterpret_cast<const float4*>(feat + (size_t)src * NDIM)[lane];
    float* p = agg + (size_t)dst * NDIM + lane * 4;
    atomicAdd(p + 0, v.x);
    atomicAdd(p + 1, v.y);
    atomicAdd(p + 2, v.z);
    atomicAdd(p + 3, v.w);
    if (deg != nullptr && lane == 0) atomicAdd(deg + dst, 1.0f);
}

// Fused SAGE linear: out[i][:] = act( (agg[i]/max(deg[i],1)) @ Wl^T + self[i] @ Wr^T + b )
// Implemented as tiled GEMM with A = [mean | self] (K=256), B = wcat[256][128].
// BM=64, BN=128, BK=32, 256 threads, 4x8 micro-tile per thread.
template <bool RELU>
__global__ __launch_bounds__(256) void sage_gemm_kernel(
    const float* __restrict__ agg, const float* __restrict__ deg,
    const float* __restrict__ selff, const float* __restrict__ wcat,
    const float* __restrict__ bias, float* __restrict__ out, int M)
{
    __shared__ float As[64][36];   // padded: stride 36 floats (16B-aligned, conflict-light)
    __shared__ float Bs[32][128];

    const int t  = threadIdx.x;
    const int tx = t & 15;    // 16 col-groups of 8 cols
    const int ty = t >> 4;    // 16 row-groups of 4 rows
    const int bm = blockIdx.x * 64;

    float acc[4][8];
#pragma unroll
    for (int i = 0; i < 4; ++i)
#pragma unroll
        for (int j = 0; j < 8; ++j) acc[i][j] = 0.0f;

    for (int kc = 0; kc < 256; kc += 32) {
        // ---- load A tile (64 rows x 32 k) : 512 float4, 2 per thread ----
#pragma unroll
        for (int i = 0; i < 2; ++i) {
            int idx = t + i * 256;       // 0..511
            int r   = idx >> 3;          // row within tile
            int kq  = idx & 7;           // float4 index within the 32-k chunk
            int row = bm + r;
            if (row >= M) row = M - 1;   // clamp (stores are guarded)
            int k = kc + kq * 4;
            float4 v;
            if (k < 128) {
                v = *reinterpret_cast<const float4*>(agg + (size_t)row * 128 + k);
                float inv = 1.0f / fmaxf(deg[row], 1.0f);
                v.x *= inv; v.y *= inv; v.z *= inv; v.w *= inv;
            } else {
                v = *reinterpret_cast<const float4*>(selff + (size_t)row * 128 + (k - 128));
            }
            *reinterpret_cast<float4*>(&As[r][kq * 4]) = v;
        }
        // ---- load B tile (32 k x 128 cols) : 1024 float4, 4 per thread ----
#pragma unroll
        for (int i = 0; i < 4; ++i) {
            int idx = t + i * 256;       // 0..1023
            int r   = idx >> 5;          // k within chunk
            int c4  = idx & 31;          // float4 col index
            float4 v = *reinterpret_cast<const float4*>(wcat + (size_t)(kc + r) * 128 + c4 * 4);
            *reinterpret_cast<float4*>(&Bs[r][c4 * 4]) = v;
        }
        __syncthreads();

#pragma unroll
        for (int kk = 0; kk < 32; ++kk) {
            float a[4];
#pragma unroll
            for (int i = 0; i < 4; ++i) a[i] = As[ty * 4 + i][kk];
            float4 b0 = *reinterpret_cast<const float4*>(&Bs[kk][tx * 8]);
            float4 b1 = *reinterpret_cast<const float4*>(&Bs[kk][tx * 8 + 4]);
            float b[8] = {b0.x, b0.y, b0.z, b0.w, b1.x, b1.y, b1.z, b1.w};
#pragma unroll
            for (int i = 0; i < 4; ++i)
#pragma unroll
                for (int j = 0; j < 8; ++j) acc[i][j] += a[i] * b[j];
        }
        __syncthreads();
    }

    // ---- epilogue: bias (+ReLU), store ----
    float4 bb0 = *reinterpret_cast<const float4*>(bias + tx * 8);
    float4 bb1 = *reinterpret_cast<const float4*>(bias + tx * 8 + 4);
    float bl[8] = {bb0.x, bb0.y, bb0.z, bb0.w, bb1.x, bb1.y, bb1.z, bb1.w};
#pragma unroll
    for (int i = 0; i < 4; ++i) {
        int row = bm + ty * 4 + i;
        if (row < M) {
            float o[8];
#pragma unroll
            for (int j = 0; j < 8; ++j) {
                float v = acc[i][j] + bl[j];
                if (RELU) v = fmaxf(v, 0.0f);
                o[j] = v;
            }
            float* p = out + (size_t)row * 128 + tx * 8;
            *reinterpret_cast<float4*>(p)     = make_float4(o[0], o[1], o[2], o[3]);
            *reinterpret_cast<float4*>(p + 4) = make_float4(o[4], o[5], o[6], o[7]);
        }
    }
}

extern "C" void kernel_launch(void* const* d_in, const int* in_sizes, int n_in,
                              void* d_out, int out_size, void* d_ws, size_t ws_size,
                              hipStream_t stream)
{
    const float* x    = (const float*)d_in[0];
    const int*   ei   = (const int*)d_in[1];
    const float* W1_l = (const float*)d_in[2];
    const float* b1_l = (const float*)d_in[3];
    const float* W1_r = (const float*)d_in[4];
    const float* W2_l = (const float*)d_in[5];
    const float* b2_l = (const float*)d_in[6];
    const float* W2_r = (const float*)d_in[7];
    float* out = (float*)d_out;

    const int N = in_sizes[0] / NDIM;      // 100000
    const int E = in_sizes[1] / 2;         // 1600000

    // Workspace layout (h lives in d_out; safe because each GEMM block reads
    // only its own rows of `selff` before overwriting them in its epilogue):
    //   deg  : N floats
    //   agg  : N*128 floats
    //   wc1  : 256*128 floats
    //   wc2  : 256*128 floats
    char* ws = (char*)d_ws;
    size_t off = 0;
    float* deg = (float*)(ws + off);
    off += ((size_t)N * 4 + 255) & ~(size_t)255;
    float* agg = (float*)(ws + off);
    off += (size_t)N * NDIM * 4;
    float* wc1 = (float*)(ws + off);
    off += 256 * 128 * 4;
    float* wc2 = (float*)(ws + off);

    // Zero accumulators (ws is poisoned 0xAA before every launch).
    hipMemsetAsync(deg, 0, (size_t)N * 4, stream);
    hipMemsetAsync(agg, 0, (size_t)N * NDIM * 4, stream);

    // Transposed/concatenated weights.
    build_wcat_kernel<<<(256 * 128 + 255) / 256, 256, 0, stream>>>(
        W1_l, W1_r, W2_l, W2_r, wc1, wc2);

    // ---- Layer 1 ----
    int scatter_blocks = (E + 7) / 8;       // 8 edges per 256-thread block
    scatter_kernel<<<scatter_blocks, 256, 0, stream>>>(x, ei, agg, deg, E);

    int gemm_blocks = (N + 63) / 64;
    float* h = out;                          // layer-1 output lives in d_out
    sage_gemm_kernel<true><<<gemm_blocks, 256, 0, stream>>>(
        agg, deg, x, wc1, b1_l, h, N);

    // ---- Layer 2 ----
    hipMemsetAsync(agg, 0, (size_t)N * NDIM * 4, stream);
    scatter_kernel<<<scatter_blocks, 256, 0, stream>>>(h, ei, agg, nullptr, E);
    sage_gemm_kernel<false><<<gemm_blocks, 256, 0, stream>>>(
        agg, deg, h, wc2, b2_l, out, N);
}

// Round 4
// 748.253 us; speedup vs baseline: 7.7262x; 7.7262x over previous
//
#include <hip/hip_runtime.h>
#include <hip/hip_bf16.h>

// Problem constants (from reference): N=100000 nodes, E=1600000 edges, D=128.
#define NDIM 128

// ---------------------------------------------------------------------------
// Weight prep: Wcat[k][j], k<128 -> W_l[j][k] (mean path), k>=128 -> W_r[j][k-128]
// ---------------------------------------------------------------------------
__global__ __launch_bounds__(256) void build_wcat_kernel(
    const float* __restrict__ W1l, const float* __restrict__ W1r,
    const float* __restrict__ W2l, const float* __restrict__ W2r,
    float* __restrict__ wc1, float* __restrict__ wc2)
{
    int idx = blockIdx.x * 256 + threadIdx.x;
    if (idx >= 256 * 128) return;
    int k = idx >> 7;
    int j = idx & 127;
    float v1, v2;
    if (k < 128) {
        v1 = W1l[j * 128 + k];
        v2 = W2l[j * 128 + k];
    } else {
        v1 = W1r[j * 128 + (k - 128)];
        v2 = W2r[j * 128 + (k - 128)];
    }
    wc1[idx] = v1;
    wc2[idx] = v2;
}

// ---------------------------------------------------------------------------
// CSR build: deg count -> exclusive prefix sum -> fill (atomic slot alloc).
// After fill, off[i] == start_i + deg_i (i.e. end); aggregation uses end-cnt.
// ---------------------------------------------------------------------------
__global__ __launch_bounds__(256) void deg_kernel(
    const int* __restrict__ ei, int* __restrict__ deg_i, int E)
{
    int e = blockIdx.x * 256 + threadIdx.x;
    if (e < E) atomicAdd(&deg_i[ei[E + e]], 1);
}

__global__ __launch_bounds__(256) void block_reduce_kernel(
    const int* __restrict__ deg_i, int* __restrict__ bsum, int N)
{
    __shared__ int s[256];
    int i = blockIdx.x * 256 + threadIdx.x;
    s[threadIdx.x] = (i < N) ? deg_i[i] : 0;
    __syncthreads();
    for (int st = 128; st > 0; st >>= 1) {
        if (threadIdx.x < st) s[threadIdx.x] += s[threadIdx.x + st];
        __syncthreads();
    }
    if (threadIdx.x == 0) bsum[blockIdx.x] = s[0];
}

__global__ void scan_bsum_kernel(int* __restrict__ bsum, int nb)
{
    if (threadIdx.x == 0 && blockIdx.x == 0) {
        int acc = 0;
        for (int i = 0; i < nb; ++i) { int v = bsum[i]; bsum[i] = acc; acc += v; }
    }
}

__global__ __launch_bounds__(256) void block_scan_kernel(
    const int* __restrict__ deg_i, const int* __restrict__ bsum,
    int* __restrict__ off, int N)
{
    __shared__ int s[256];
    int i = blockIdx.x * 256 + threadIdx.x;
    int v = (i < N) ? deg_i[i] : 0;
    s[threadIdx.x] = v;
    __syncthreads();
    for (int st = 1; st < 256; st <<= 1) {           // inclusive Hillis-Steele
        int t = (threadIdx.x >= st) ? s[threadIdx.x - st] : 0;
        __syncthreads();
        s[threadIdx.x] += t;
        __syncthreads();
    }
    if (i < N) off[i] = bsum[blockIdx.x] + s[threadIdx.x] - v;   // exclusive
}

__global__ __launch_bounds__(256) void fill_kernel(
    const int* __restrict__ ei, int* __restrict__ off, int* __restrict__ csr, int E)
{
    int e = blockIdx.x * 256 + threadIdx.x;
    if (e < E) {
        int dst = ei[E + e];
        int pos = atomicAdd(&off[dst], 1);
        csr[pos] = ei[e];          // src
    }
}

// ---------------------------------------------------------------------------
// Gather aggregation: one 64-lane wave per node; lane l owns dims 2l, 2l+1.
// mean[node][:] = (1/max(deg,1)) * sum_{e in CSR[node]} feat[src_e][:]
// ---------------------------------------------------------------------------
__global__ __launch_bounds__(256) void aggregate_kernel(
    const float* __restrict__ feat, const int* __restrict__ csr,
    const int* __restrict__ off, const int* __restrict__ deg_i,
    float* __restrict__ mean, int N)
{
    int node = (blockIdx.x * 256 + threadIdx.x) >> 6;
    if (node >= N) return;
    int lane = threadIdx.x & 63;
    int cnt  = deg_i[node];
    int end  = off[node];          // == start + cnt after fill
    int start = end - cnt;

    float ax = 0.0f, ay = 0.0f;
    int e = start;
    for (; e + 4 <= end; e += 4) {                 // 4-deep ILP gather
        int s0 = csr[e], s1 = csr[e + 1], s2 = csr[e + 2], s3 = csr[e + 3];
        float2 v0 = *reinterpret_cast<const float2*>(feat + (size_t)s0 * NDIM + lane * 2);
        float2 v1 = *reinterpret_cast<const float2*>(feat + (size_t)s1 * NDIM + lane * 2);
        float2 v2 = *reinterpret_cast<const float2*>(feat + (size_t)s2 * NDIM + lane * 2);
        float2 v3 = *reinterpret_cast<const float2*>(feat + (size_t)s3 * NDIM + lane * 2);
        ax += v0.x + v1.x + v2.x + v3.x;
        ay += v0.y + v1.y + v2.y + v3.y;
    }
    for (; e < end; ++e) {
        int s0 = csr[e];
        float2 v0 = *reinterpret_cast<const float2*>(feat + (size_t)s0 * NDIM + lane * 2);
        ax += v0.x;
        ay += v0.y;
    }
    float inv = 1.0f / fmaxf((float)cnt, 1.0f);
    *reinterpret_cast<float2*>(mean + (size_t)node * NDIM + lane * 2) =
        make_float2(ax * inv, ay * inv);
}

// ---------------------------------------------------------------------------
// Fused SAGE linear: out[i][:] = act( mean[i] @ Wl^T + self[i] @ Wr^T + b )
// Tiled GEMM, A = [mean | self] (K=256), B = wcat[256][128].
// BM=64, BN=128, BK=32, 256 threads, 4x8 micro-tile per thread.
// ---------------------------------------------------------------------------
template <bool RELU>
__global__ __launch_bounds__(256) void sage_gemm_kernel(
    const float* __restrict__ mean, const float* __restrict__ selff,
    const float* __restrict__ wcat, const float* __restrict__ bias,
    float* __restrict__ out, int M)
{
    __shared__ float As[64][36];
    __shared__ float Bs[32][128];

    const int t  = threadIdx.x;
    const int tx = t & 15;
    const int ty = t >> 4;
    const int bm = blockIdx.x * 64;

    float acc[4][8];
#pragma unroll
    for (int i = 0; i < 4; ++i)
#pragma unroll
        for (int j = 0; j < 8; ++j) acc[i][j] = 0.0f;

    for (int kc = 0; kc < 256; kc += 32) {
#pragma unroll
        for (int i = 0; i < 2; ++i) {
            int idx = t + i * 256;
            int r   = idx >> 3;
            int kq  = idx & 7;
            int row = bm + r;
            if (row >= M) row = M - 1;
            int k = kc + kq * 4;
            float4 v;
            if (k < 128) {
                v = *reinterpret_cast<const float4*>(mean + (size_t)row * 128 + k);
            } else {
                v = *reinterpret_cast<const float4*>(selff + (size_t)row * 128 + (k - 128));
            }
            *reinterpret_cast<float4*>(&As[r][kq * 4]) = v;
        }
#pragma unroll
        for (int i = 0; i < 4; ++i) {
            int idx = t + i * 256;
            int r   = idx >> 5;
            int c4  = idx & 31;
            float4 v = *reinterpret_cast<const float4*>(wcat + (size_t)(kc + r) * 128 + c4 * 4);
            *reinterpret_cast<float4*>(&Bs[r][c4 * 4]) = v;
        }
        __syncthreads();

#pragma unroll
        for (int kk = 0; kk < 32; ++kk) {
            float a[4];
#pragma unroll
            for (int i = 0; i < 4; ++i) a[i] = As[ty * 4 + i][kk];
            float4 b0 = *reinterpret_cast<const float4*>(&Bs[kk][tx * 8]);
            float4 b1 = *reinterpret_cast<const float4*>(&Bs[kk][tx * 8 + 4]);
            float b[8] = {b0.x, b0.y, b0.z, b0.w, b1.x, b1.y, b1.z, b1.w};
#pragma unroll
            for (int i = 0; i < 4; ++i)
#pragma unroll
                for (int j = 0; j < 8; ++j) acc[i][j] += a[i] * b[j];
        }
        __syncthreads();
    }

    float4 bb0 = *reinterpret_cast<const float4*>(bias + tx * 8);
    float4 bb1 = *reinterpret_cast<const float4*>(bias + tx * 8 + 4);
    float bl[8] = {bb0.x, bb0.y, bb0.z, bb0.w, bb1.x, bb1.y, bb1.z, bb1.w};
#pragma unroll
    for (int i = 0; i < 4; ++i) {
        int row = bm + ty * 4 + i;
        if (row < M) {
            float o[8];
#pragma unroll
            for (int j = 0; j < 8; ++j) {
                float v = acc[i][j] + bl[j];
                if (RELU) v = fmaxf(v, 0.0f);
                o[j] = v;
            }
            float* p = out + (size_t)row * 128 + tx * 8;
            *reinterpret_cast<float4*>(p)     = make_float4(o[0], o[1], o[2], o[3]);
            *reinterpret_cast<float4*>(p + 4) = make_float4(o[4], o[5], o[6], o[7]);
        }
    }
}

// ---------------------------------------------------------------------------
extern "C" void kernel_launch(void* const* d_in, const int* in_sizes, int n_in,
                              void* d_out, int out_size, void* d_ws, size_t ws_size,
                              hipStream_t stream)
{
    const float* x    = (const float*)d_in[0];
    const int*   ei   = (const int*)d_in[1];
    const float* W1_l = (const float*)d_in[2];
    const float* b1_l = (const float*)d_in[3];
    const float* W1_r = (const float*)d_in[4];
    const float* W2_l = (const float*)d_in[5];
    const float* b2_l = (const float*)d_in[6];
    const float* W2_r = (const float*)d_in[7];
    float* out = (float*)d_out;

    const int N = in_sizes[0] / NDIM;      // 100000
    const int E = in_sizes[1] / 2;         // 1600000
    const int NB = (N + 255) / 256;        // scan blocks (391)

    // Workspace layout:
    //   deg_i : N ints
    //   off   : N ints   (becomes end-offsets after fill)
    //   bsum  : NB ints
    //   csr   : E ints
    //   mean  : N*128 floats
    //   wc1/2 : 256*128 floats each
    char* ws = (char*)d_ws;
    size_t o = 0;
    auto alloc = [&](size_t bytes) { void* p = ws + o; o += (bytes + 255) & ~(size_t)255; return p; };
    int*   deg_i = (int*)  alloc((size_t)N * 4);
    int*   off   = (int*)  alloc((size_t)N * 4);
    int*   bsum  = (int*)  alloc((size_t)NB * 4);
    int*   csr   = (int*)  alloc((size_t)E * 4);
    float* mean  = (float*)alloc((size_t)N * NDIM * 4);
    float* wc1   = (float*)alloc(256 * 128 * 4);
    float* wc2   = (float*)alloc(256 * 128 * 4);

    hipMemsetAsync(deg_i, 0, (size_t)N * 4, stream);

    build_wcat_kernel<<<(256 * 128 + 255) / 256, 256, 0, stream>>>(
        W1_l, W1_r, W2_l, W2_r, wc1, wc2);

    // ---- CSR build (once; shared by both layers) ----
    int eb = (E + 255) / 256;
    deg_kernel<<<eb, 256, 0, stream>>>(ei, deg_i, E);
    block_reduce_kernel<<<NB, 256, 0, stream>>>(deg_i, bsum, N);
    scan_bsum_kernel<<<1, 64, 0, stream>>>(bsum, NB);
    block_scan_kernel<<<NB, 256, 0, stream>>>(deg_i, bsum, off, N);
    fill_kernel<<<eb, 256, 0, stream>>>(ei, off, csr, E);

    int agg_blocks  = (N * 64 + 255) / 256;   // one wave per node
    int gemm_blocks = (N + 63) / 64;
    float* h = out;                            // layer-1 output lives in d_out

    // ---- Layer 1 ----
    aggregate_kernel<<<agg_blocks, 256, 0, stream>>>(x, csr, off, deg_i, mean, N);
    sage_gemm_kernel<true><<<gemm_blocks, 256, 0, stream>>>(
        mean, x, wc1, b1_l, h, N);

    // ---- Layer 2 ----
    aggregate_kernel<<<agg_blocks, 256, 0, stream>>>(h, csr, off, deg_i, mean, N);
    sage_gemm_kernel<false><<<gemm_blocks, 256, 0, stream>>>(
        mean, h, wc2, b2_l, out, N);
}

// Round 8
// 555.348 us; speedup vs baseline: 10.4100x; 1.3474x over previous
//
#include <hip/hip_runtime.h>
#include <hip/hip_bf16.h>

// N=100000 nodes, E=1600000 edges, D=128 throughout.
#define NDIM 128

using short8 = __attribute__((ext_vector_type(8))) short;
using f32x4  = __attribute__((ext_vector_type(4))) float;

__device__ __forceinline__ float bf_lo(unsigned int u) {
    unsigned int v = u << 16; return __builtin_bit_cast(float, v);
}
__device__ __forceinline__ float bf_hi(unsigned int u) {
    unsigned int v = u & 0xFFFF0000u; return __builtin_bit_cast(float, v);
}
__device__ __forceinline__ unsigned short f2bf(float f) {
    unsigned int u = __builtin_bit_cast(unsigned int, f);
    unsigned int r = (u + 0x7FFFu + ((u >> 16) & 1u)) >> 16;   // RNE
    return (unsigned short)r;
}

// ---------------------------------------------------------------------------
// x (fp32) -> xb (bf16), 4 elems/thread
// ---------------------------------------------------------------------------
__global__ __launch_bounds__(256) void cast_bf16_kernel(
    const float* __restrict__ x, unsigned short* __restrict__ xb, int n4)
{
    int i = blockIdx.x * 256 + threadIdx.x;
    if (i >= n4) return;
    float4 v = reinterpret_cast<const float4*>(x)[i];
    ushort4 o;
    o.x = f2bf(v.x); o.y = f2bf(v.y); o.z = f2bf(v.z); o.w = f2bf(v.w);
    reinterpret_cast<ushort4*>(xb)[i] = o;
}

// ---------------------------------------------------------------------------
// Transposed bf16 weights: wt[j][k], k<128 -> W_l[j][k], else W_r[j][k-128].
// (B-operand reads wt[col][k..k+8] contiguously.)
// ---------------------------------------------------------------------------
__global__ __launch_bounds__(256) void build_wt_kernel(
    const float* __restrict__ W1l, const float* __restrict__ W1r,
    const float* __restrict__ W2l, const float* __restrict__ W2r,
    unsigned short* __restrict__ wt1, unsigned short* __restrict__ wt2)
{
    int idx = blockIdx.x * 256 + threadIdx.x;     // [j][k], j=idx>>8, k=idx&255
    if (idx >= 128 * 256) return;
    int j = idx >> 8, k = idx & 255;
    float v1 = (k < 128) ? W1l[j * 128 + k] : W1r[j * 128 + (k - 128)];
    float v2 = (k < 128) ? W2l[j * 128 + k] : W2r[j * 128 + (k - 128)];
    wt1[idx] = f2bf(v1);
    wt2[idx] = f2bf(v2);
}

// ---------------------------------------------------------------------------
// CSR build: degree count -> exclusive scan -> fill (atomic slot alloc).
// 4 edges/thread for atomic-latency ILP.
// ---------------------------------------------------------------------------
__global__ __launch_bounds__(256) void deg_kernel(
    const int* __restrict__ ei, int* __restrict__ deg_i, int E)
{
    int e0 = (blockIdx.x * 256 + threadIdx.x) * 4;
    if (e0 + 4 <= E) {
        int4 d = *reinterpret_cast<const int4*>(ei + E + e0);
        atomicAdd(&deg_i[d.x], 1);
        atomicAdd(&deg_i[d.y], 1);
        atomicAdd(&deg_i[d.z], 1);
        atomicAdd(&deg_i[d.w], 1);
    } else {
        for (int e = e0; e < E; ++e) atomicAdd(&deg_i[ei[E + e]], 1);
    }
}

__global__ __launch_bounds__(256) void block_reduce_kernel(
    const int* __restrict__ deg_i, int* __restrict__ bsum, int N)
{
    __shared__ int s[256];
    int i = blockIdx.x * 256 + threadIdx.x;
    s[threadIdx.x] = (i < N) ? deg_i[i] : 0;
    __syncthreads();
    for (int st = 128; st > 0; st >>= 1) {
        if (threadIdx.x < st) s[threadIdx.x] += s[threadIdx.x + st];
        __syncthreads();
    }
    if (threadIdx.x == 0) bsum[blockIdx.x] = s[0];
}

__global__ __launch_bounds__(512) void scan_bsum_kernel(int* __restrict__ bsum, int nb)
{
    __shared__ int s[512];
    int i = threadIdx.x;
    int v = (i < nb) ? bsum[i] : 0;
    s[i] = v;
    __syncthreads();
    for (int st = 1; st < 512; st <<= 1) {
        int t = (i >= st) ? s[i - st] : 0;
        __syncthreads();
        s[i] += t;
        __syncthreads();
    }
    if (i < nb) bsum[i] = s[i] - v;                 // exclusive
}

__global__ __launch_bounds__(256) void block_scan_kernel(
    const int* __restrict__ deg_i, const int* __restrict__ bsum,
    int* __restrict__ off, int N)
{
    __shared__ int s[256];
    int i = blockIdx.x * 256 + threadIdx.x;
    int v = (i < N) ? deg_i[i] : 0;
    s[threadIdx.x] = v;
    __syncthreads();
    for (int st = 1; st < 256; st <<= 1) {
        int t = (threadIdx.x >= st) ? s[threadIdx.x - st] : 0;
        __syncthreads();
        s[threadIdx.x] += t;
        __syncthreads();
    }
    if (i < N) off[i] = bsum[blockIdx.x] + s[threadIdx.x] - v;   // exclusive
}

__global__ __launch_bounds__(256) void fill_kernel(
    const int* __restrict__ ei, int* __restrict__ off, int* __restrict__ csr, int E)
{
    int e0 = (blockIdx.x * 256 + threadIdx.x) * 4;
    if (e0 + 4 <= E) {
        int4 sr = *reinterpret_cast<const int4*>(ei + e0);
        int4 d  = *reinterpret_cast<const int4*>(ei + E + e0);
        int p0 = atomicAdd(&off[d.x], 1);     // 4 independent returning atomics
        int p1 = atomicAdd(&off[d.y], 1);     // in flight -> latency overlap
        int p2 = atomicAdd(&off[d.z], 1);
        int p3 = atomicAdd(&off[d.w], 1);
        csr[p0] = sr.x; csr[p1] = sr.y; csr[p2] = sr.z; csr[p3] = sr.w;
    } else {
        for (int e = e0; e < E; ++e) {
            int pos = atomicAdd(&off[ei[E + e]], 1);
            csr[pos] = ei[e];
        }
    }
}

// ---------------------------------------------------------------------------
// Gather-mean (bf16 in, bf16 out): one 64-lane wave per node; lane owns dims
// 2l, 2l+1 (one packed uint per row). fp32 accumulation, 4-deep ILP.
// ---------------------------------------------------------------------------
__global__ __launch_bounds__(256) void aggregate_kernel(
    const unsigned short* __restrict__ feat, const int* __restrict__ csr,
    const int* __restrict__ off, const int* __restrict__ deg_i,
    unsigned short* __restrict__ meanb, int N)
{
    int node = (blockIdx.x * 256 + threadIdx.x) >> 6;
    if (node >= N) return;
    int lane = threadIdx.x & 63;
    int cnt  = deg_i[node];
    int end  = off[node];              // start + cnt after fill
    int e    = end - cnt;

    const unsigned int* fp = reinterpret_cast<const unsigned int*>(feat);
    float ax = 0.0f, ay = 0.0f;
    for (; e + 4 <= end; e += 4) {
        int s0 = csr[e], s1 = csr[e + 1], s2 = csr[e + 2], s3 = csr[e + 3];
        unsigned int u0 = fp[s0 * 64 + lane];
        unsigned int u1 = fp[s1 * 64 + lane];
        unsigned int u2 = fp[s2 * 64 + lane];
        unsigned int u3 = fp[s3 * 64 + lane];
        ax += bf_lo(u0) + bf_lo(u1) + bf_lo(u2) + bf_lo(u3);
        ay += bf_hi(u0) + bf_hi(u1) + bf_hi(u2) + bf_hi(u3);
    }
    for (; e < end; ++e) {
        unsigned int u0 = fp[csr[e] * 64 + lane];
        ax += bf_lo(u0);
        ay += bf_hi(u0);
    }
    float inv = 1.0f / fmaxf((float)cnt, 1.0f);
    unsigned int packed = ((unsigned int)f2bf(ay * inv) << 16) | f2bf(ax * inv);
    reinterpret_cast<unsigned int*>(meanb)[node * 64 + lane] = packed;
}

// ---------------------------------------------------------------------------
// MFMA SAGE linear: out[i][:] = act( mean[i]@Wl^T + self[i]@Wr^T + b ).
// Zero LDS, zero barriers: per-wave 32x64 output tile, A/B frags loaded from
// L2-resident global. Block = 4 waves (2M x 2N) -> 64 rows x 128 cols.
// mfma_f32_16x16x32_bf16; C/D: col=lane&15, row=(lane>>4)*4+i (m89-verified).
// K-fragment mapping is any consistent permutation (cancels between A and B).
// ---------------------------------------------------------------------------
template <bool RELU, bool OUTBF>
__global__ __launch_bounds__(256) void sage_gemm_kernel(
    const unsigned short* meanb, const unsigned short* selfb,
    const unsigned short* __restrict__ wt, const float* __restrict__ bias,
    void* outv, int M)
{
    const int t    = threadIdx.x;
    const int lane = t & 63;
    const int wid  = t >> 6;        // 0..3
    const int wm   = wid >> 1;      // 0..1 (M)
    const int wn   = wid & 1;       // 0..1 (N)
    const int l15  = lane & 15;
    const int g    = lane >> 4;     // 0..3

    const int bm = blockIdx.x * 64;
    int rowA[2];
#pragma unroll
    for (int r = 0; r < 2; ++r) {
        int rr = bm + wm * 32 + r * 16 + l15;
        rowA[r] = (rr < M) ? rr : (M - 1);
    }
    const int colbase = wn * 64;

    f32x4 acc[2][4];
#pragma unroll
    for (int r = 0; r < 2; ++r)
#pragma unroll
        for (int c = 0; c < 4; ++c) acc[r][c] = (f32x4){0.f, 0.f, 0.f, 0.f};

#pragma unroll
    for (int s = 0; s < 8; ++s) {
        const unsigned short* abase = (s < 4) ? meanb : selfb;
        const int koffA = (s & 3) * 32 + g * 8;     // within the 128-wide half
        const int koffB = s * 32 + g * 8;           // full 256-wide K
        short8 a[2], b[4];
#pragma unroll
        for (int r = 0; r < 2; ++r)
            a[r] = *reinterpret_cast<const short8*>(abase + (size_t)rowA[r] * 128 + koffA);
#pragma unroll
        for (int c = 0; c < 4; ++c)
            b[c] = *reinterpret_cast<const short8*>(wt + (size_t)(colbase + c * 16 + l15) * 256 + koffB);
#pragma unroll
        for (int r = 0; r < 2; ++r)
#pragma unroll
            for (int c = 0; c < 4; ++c)
                acc[r][c] = __builtin_amdgcn_mfma_f32_16x16x32_bf16(a[r], b[c], acc[r][c], 0, 0, 0);
    }

    // epilogue: bias (+ReLU), store fp32 or bf16
#pragma unroll
    for (int c = 0; c < 4; ++c) {
        int col = colbase + c * 16 + l15;
        float bs = bias[col];
#pragma unroll
        for (int r = 0; r < 2; ++r) {
#pragma unroll
            for (int i = 0; i < 4; ++i) {
                int row = bm + wm * 32 + r * 16 + g * 4 + i;
                if (row < M) {
                    float v = acc[r][c][i] + bs;
                    if (RELU) v = fmaxf(v, 0.0f);
                    if (OUTBF)
                        ((unsigned short*)outv)[(size_t)row * 128 + col] = f2bf(v);
                    else
                        ((float*)outv)[(size_t)row * 128 + col] = v;
                }
            }
        }
    }
}

// ---------------------------------------------------------------------------
extern "C" void kernel_launch(void* const* d_in, const int* in_sizes, int n_in,
                              void* d_out, int out_size, void* d_ws, size_t ws_size,
                              hipStream_t stream)
{
    const float* x    = (const float*)d_in[0];
    const int*   ei   = (const int*)d_in[1];
    const float* W1_l = (const float*)d_in[2];
    const float* b1_l = (const float*)d_in[3];
    const float* W1_r = (const float*)d_in[4];
    const float* W2_l = (const float*)d_in[5];
    const float* b2_l = (const float*)d_in[6];
    const float* W2_r = (const float*)d_in[7];
    float* out = (float*)d_out;

    const int N  = in_sizes[0] / NDIM;     // 100000
    const int E  = in_sizes[1] / 2;        // 1600000
    const int NB = (N + 255) / 256;        // 391 (<=512 for scan kernel)

    // Workspace (~58.1 MB):
    char* ws = (char*)d_ws;
    size_t o = 0;
    auto alloc = [&](size_t bytes) { void* p = ws + o; o += (bytes + 255) & ~(size_t)255; return p; };
    int*            deg_i = (int*)           alloc((size_t)N * 4);
    int*            off   = (int*)           alloc((size_t)N * 4);
    int*            bsum  = (int*)           alloc((size_t)NB * 4);
    int*            csr   = (int*)           alloc((size_t)E * 4);
    unsigned short* xb    = (unsigned short*)alloc((size_t)N * NDIM * 2);  // doubles as hb
    unsigned short* meanb = (unsigned short*)alloc((size_t)N * NDIM * 2);
    unsigned short* wt1   = (unsigned short*)alloc(128 * 256 * 2);
    unsigned short* wt2   = (unsigned short*)alloc(128 * 256 * 2);

    hipMemsetAsync(deg_i, 0, (size_t)N * 4, stream);

    // Prep: bf16 cast + transposed bf16 weights
    int n4 = (N * NDIM) / 4;
    cast_bf16_kernel<<<(n4 + 255) / 256, 256, 0, stream>>>(x, xb, n4);
    build_wt_kernel<<<(128 * 256 + 255) / 256, 256, 0, stream>>>(
        W1_l, W1_r, W2_l, W2_r, wt1, wt2);

    // CSR build (once; shared by both layers)
    int eb4 = (E / 4 + 255) / 256;
    deg_kernel<<<eb4, 256, 0, stream>>>(ei, deg_i, E);
    block_reduce_kernel<<<NB, 256, 0, stream>>>(deg_i, bsum, N);
    scan_bsum_kernel<<<1, 512, 0, stream>>>(bsum, NB);
    block_scan_kernel<<<NB, 256, 0, stream>>>(deg_i, bsum, off, N);
    fill_kernel<<<eb4, 256, 0, stream>>>(ei, off, csr, E);

    int agg_blocks  = (N + 3) / 4;          // 4 nodes (waves) per 256-thr block
    int gemm_blocks = (N + 63) / 64;
    unsigned short* hb = xb;                 // layer-1 bf16 output aliases xb:
                                             // each gemm block reads only its own
                                             // rows of selfb before overwriting.

    // ---- Layer 1 ----
    aggregate_kernel<<<agg_blocks, 256, 0, stream>>>(xb, csr, off, deg_i, meanb, N);
    sage_gemm_kernel<true, true><<<gemm_blocks, 256, 0, stream>>>(
        meanb, xb, wt1, b1_l, hb, N);

    // ---- Layer 2 ----
    aggregate_kernel<<<agg_blocks, 256, 0, stream>>>(hb, csr, off, deg_i, meanb, N);
    sage_gemm_kernel<false, false><<<gemm_blocks, 256, 0, stream>>>(
        meanb, hb, wt2, b2_l, out, N);
}

// Round 12
// 405.766 us; speedup vs baseline: 14.2475x; 1.3686x over previous
//
#include <hip/hip_runtime.h>
#include <hip/hip_bf16.h>

// N=100000 nodes, E=1600000 edges, D=128 throughout.
#define NDIM 128
#define DPB 128          // dst nodes per bucket (==2^7; bucket = dst>>7)
#define CAP 4096         // max edges per bucket (mean 2048; Chernoff-safe)
#define NBUCK_MAX 1024   // LDS sizing; runtime nbuck = ceil(N/128) = 782
#define NBIN 256         // blocks in bin_kernel

using short8 = __attribute__((ext_vector_type(8))) short;
using f32x4  = __attribute__((ext_vector_type(4))) float;

__device__ __forceinline__ float bf_lo(unsigned int u) {
    unsigned int v = u << 16; return __builtin_bit_cast(float, v);
}
__device__ __forceinline__ float bf_hi(unsigned int u) {
    unsigned int v = u & 0xFFFF0000u; return __builtin_bit_cast(float, v);
}
__device__ __forceinline__ unsigned short f2bf(float f) {
    unsigned int u = __builtin_bit_cast(unsigned int, f);
    unsigned int r = (u + 0x7FFFu + ((u >> 16) & 1u)) >> 16;   // RNE
    return (unsigned short)r;
}

// ---------------------------------------------------------------------------
// x (fp32) -> xb (bf16), 4 elems/thread
// ---------------------------------------------------------------------------
__global__ __launch_bounds__(256) void cast_bf16_kernel(
    const float* __restrict__ x, unsigned short* __restrict__ xb, int n4)
{
    int i = blockIdx.x * 256 + threadIdx.x;
    if (i >= n4) return;
    float4 v = reinterpret_cast<const float4*>(x)[i];
    ushort4 o;
    o.x = f2bf(v.x); o.y = f2bf(v.y); o.z = f2bf(v.z); o.w = f2bf(v.w);
    reinterpret_cast<ushort4*>(xb)[i] = o;
}

// ---------------------------------------------------------------------------
// Transposed bf16 weights: wt[j][k], k<128 -> W_l[j][k], else W_r[j][k-128].
// ---------------------------------------------------------------------------
__global__ __launch_bounds__(256) void build_wt_kernel(
    const float* __restrict__ W1l, const float* __restrict__ W1r,
    const float* __restrict__ W2l, const float* __restrict__ W2r,
    unsigned short* __restrict__ wt1, unsigned short* __restrict__ wt2)
{
    int idx = blockIdx.x * 256 + threadIdx.x;     // [j][k]
    if (idx >= 128 * 256) return;
    int j = idx >> 8, k = idx & 255;
    float v1 = (k < 128) ? W1l[j * 128 + k] : W1r[j * 128 + (k - 128)];
    float v2 = (k < 128) ? W2l[j * 128 + k] : W2r[j * 128 + (k - 128)];
    wt1[idx] = f2bf(v1);
    wt2[idx] = f2bf(v2);
}

// ---------------------------------------------------------------------------
// Pass A: LDS-binned edge partition. Each block histograms its edge tile into
// LDS (782 buckets), reserves per-bucket global ranges with ONE atomic per
// (block,bucket) (~200K global atomics vs 3.2M before), then appends packed
// (local_dst<<17 | src) records. Appends are block-contiguous per bucket.
// ---------------------------------------------------------------------------
__global__ __launch_bounds__(256) void bin_kernel(
    const int* __restrict__ ei, int* __restrict__ gcnt,
    unsigned int* __restrict__ pairs, int E, int nbuck, int per)
{
    __shared__ int hist[NBUCK_MAX];
    __shared__ int lbase[NBUCK_MAX];
    const int tid = threadIdx.x;
    const int e0 = blockIdx.x * per;
    const int e1 = min(e0 + per, E);

    for (int j = tid; j < nbuck; j += 256) hist[j] = 0;
    __syncthreads();
    for (int e = e0 + tid; e < e1; e += 256)
        atomicAdd(&hist[ei[E + e] >> 7], 1);
    __syncthreads();
    for (int j = tid; j < nbuck; j += 256) {
        int h = hist[j];
        lbase[j] = (h > 0) ? atomicAdd(&gcnt[j], h) : 0;
        hist[j] = 0;                       // reuse as running offset
    }
    __syncthreads();
    for (int e = e0 + tid; e < e1; e += 256) {
        int d = ei[E + e];
        int s = ei[e];
        int b = d >> 7;
        int r = atomicAdd(&hist[b], 1);
        int pos = lbase[b] + r;
        if (pos < CAP)                     // safety guard (statistically never)
            pairs[(size_t)b * CAP + pos] = ((unsigned)(d & 127) << 17) | (unsigned)s;
    }
}

// ---------------------------------------------------------------------------
// Exclusive scan over bucket totals (nbuck=782 <= 1024), one block.
// ---------------------------------------------------------------------------
__global__ __launch_bounds__(1024) void bucket_scan_kernel(
    const int* __restrict__ gcnt, int* __restrict__ gbase, int nbuck)
{
    __shared__ int s[1024];
    int i = threadIdx.x;
    int v = (i < nbuck) ? gcnt[i] : 0;
    s[i] = v;
    __syncthreads();
    for (int st = 1; st < 1024; st <<= 1) {
        int t = (i >= st) ? s[i - st] : 0;
        __syncthreads();
        s[i] += t;
        __syncthreads();
    }
    if (i < nbuck) gbase[i] = s[i] - v;
}

// ---------------------------------------------------------------------------
// Pass B: one block per bucket. Per-dst counts + scan in LDS; emit csr, deg,
// start coalesced. All csr writes land in one ~8KB contiguous region.
// ---------------------------------------------------------------------------
__global__ __launch_bounds__(256) void csr_build_kernel(
    const unsigned int* __restrict__ pairs, const int* __restrict__ gcnt,
    const int* __restrict__ gbase, int* __restrict__ csr,
    int* __restrict__ deg_i, int* __restrict__ start_i, int N)
{
    __shared__ int dcnt[DPB];
    __shared__ int dbase[DPB];
    const int b = blockIdx.x;
    const int tid = threadIdx.x;
    int nb = gcnt[b]; if (nb > CAP) nb = CAP;
    const unsigned int* pb = pairs + (size_t)b * CAP;

    if (tid < DPB) dcnt[tid] = 0;
    __syncthreads();
    for (int p = tid; p < nb; p += 256)
        atomicAdd(&dcnt[pb[p] >> 17], 1);
    __syncthreads();
    if (tid == 0) {
        int run = gbase[b];
        for (int d = 0; d < DPB; ++d) { dbase[d] = run; run += dcnt[d]; }
    }
    __syncthreads();
    if (tid < DPB) {
        int node = b * DPB + tid;
        if (node < N) { deg_i[node] = dcnt[tid]; start_i[node] = dbase[tid]; }
        dcnt[tid] = 0;                     // reuse as running offset
    }
    __syncthreads();
    for (int p = tid; p < nb; p += 256) {
        unsigned u = pb[p];
        int d = u >> 17;
        int r = atomicAdd(&dcnt[d], 1);
        csr[dbase[d] + r] = (int)(u & 0x1FFFFu);
    }
}

// ---------------------------------------------------------------------------
// Gather-mean (bf16 in, bf16 out): one 64-lane wave per node; lane owns dims
// 2l, 2l+1 (one packed uint per row). fp32 accumulation, 4-deep ILP.
// ---------------------------------------------------------------------------
__global__ __launch_bounds__(256) void aggregate_kernel(
    const unsigned short* __restrict__ feat, const int* __restrict__ csr,
    const int* __restrict__ start_i, const int* __restrict__ deg_i,
    unsigned short* __restrict__ meanb, int N)
{
    int node = (blockIdx.x * 256 + threadIdx.x) >> 6;
    if (node >= N) return;
    int lane = threadIdx.x & 63;
    int cnt  = deg_i[node];
    int e    = start_i[node];
    int end  = e + cnt;

    const unsigned int* fp = reinterpret_cast<const unsigned int*>(feat);
    float ax = 0.0f, ay = 0.0f;
    for (; e + 4 <= end; e += 4) {
        int s0 = csr[e], s1 = csr[e + 1], s2 = csr[e + 2], s3 = csr[e + 3];
        unsigned int u0 = fp[s0 * 64 + lane];
        unsigned int u1 = fp[s1 * 64 + lane];
        unsigned int u2 = fp[s2 * 64 + lane];
        unsigned int u3 = fp[s3 * 64 + lane];
        ax += bf_lo(u0) + bf_lo(u1) + bf_lo(u2) + bf_lo(u3);
        ay += bf_hi(u0) + bf_hi(u1) + bf_hi(u2) + bf_hi(u3);
    }
    for (; e < end; ++e) {
        unsigned int u0 = fp[csr[e] * 64 + lane];
        ax += bf_lo(u0);
        ay += bf_hi(u0);
    }
    float inv = 1.0f / fmaxf((float)cnt, 1.0f);
    unsigned int packed = ((unsigned int)f2bf(ay * inv) << 16) | f2bf(ax * inv);
    reinterpret_cast<unsigned int*>(meanb)[node * 64 + lane] = packed;
}

// ---------------------------------------------------------------------------
// MFMA SAGE linear: out[i][:] = act( mean[i]@Wl^T + self[i]@Wr^T + b ).
// Zero LDS, zero barriers: per-wave 32x64 output tile; block = 4 waves.
// ---------------------------------------------------------------------------
template <bool RELU, bool OUTBF>
__global__ __launch_bounds__(256) void sage_gemm_kernel(
    const unsigned short* meanb, const unsigned short* selfb,
    const unsigned short* __restrict__ wt, const float* __restrict__ bias,
    void* outv, int M)
{
    const int t    = threadIdx.x;
    const int lane = t & 63;
    const int wid  = t >> 6;
    const int wm   = wid >> 1;
    const int wn   = wid & 1;
    const int l15  = lane & 15;
    const int g    = lane >> 4;

    const int bm = blockIdx.x * 64;
    int rowA[2];
#pragma unroll
    for (int r = 0; r < 2; ++r) {
        int rr = bm + wm * 32 + r * 16 + l15;
        rowA[r] = (rr < M) ? rr : (M - 1);
    }
    const int colbase = wn * 64;

    f32x4 acc[2][4];
#pragma unroll
    for (int r = 0; r < 2; ++r)
#pragma unroll
        for (int c = 0; c < 4; ++c) acc[r][c] = (f32x4){0.f, 0.f, 0.f, 0.f};

#pragma unroll
    for (int s = 0; s < 8; ++s) {
        const unsigned short* abase = (s < 4) ? meanb : selfb;
        const int koffA = (s & 3) * 32 + g * 8;
        const int koffB = s * 32 + g * 8;
        short8 a[2], b[4];
#pragma unroll
        for (int r = 0; r < 2; ++r)
            a[r] = *reinterpret_cast<const short8*>(abase + (size_t)rowA[r] * 128 + koffA);
#pragma unroll
        for (int c = 0; c < 4; ++c)
            b[c] = *reinterpret_cast<const short8*>(wt + (size_t)(colbase + c * 16 + l15) * 256 + koffB);
#pragma unroll
        for (int r = 0; r < 2; ++r)
#pragma unroll
            for (int c = 0; c < 4; ++c)
                acc[r][c] = __builtin_amdgcn_mfma_f32_16x16x32_bf16(a[r], b[c], acc[r][c], 0, 0, 0);
    }

#pragma unroll
    for (int c = 0; c < 4; ++c) {
        int col = colbase + c * 16 + l15;
        float bs = bias[col];
#pragma unroll
        for (int r = 0; r < 2; ++r) {
#pragma unroll
            for (int i = 0; i < 4; ++i) {
                int row = bm + wm * 32 + r * 16 + g * 4 + i;
                if (row < M) {
                    float v = acc[r][c][i] + bs;
                    if (RELU) v = fmaxf(v, 0.0f);
                    if (OUTBF)
                        ((unsigned short*)outv)[(size_t)row * 128 + col] = f2bf(v);
                    else
                        ((float*)outv)[(size_t)row * 128 + col] = v;
                }
            }
        }
    }
}

// ---------------------------------------------------------------------------
extern "C" void kernel_launch(void* const* d_in, const int* in_sizes, int n_in,
                              void* d_out, int out_size, void* d_ws, size_t ws_size,
                              hipStream_t stream)
{
    const float* x    = (const float*)d_in[0];
    const int*   ei   = (const int*)d_in[1];
    const float* W1_l = (const float*)d_in[2];
    const float* b1_l = (const float*)d_in[3];
    const float* W1_r = (const float*)d_in[4];
    const float* W2_l = (const float*)d_in[5];
    const float* b2_l = (const float*)d_in[6];
    const float* W2_r = (const float*)d_in[7];
    float* out = (float*)d_out;

    const int N     = in_sizes[0] / NDIM;      // 100000
    const int E     = in_sizes[1] / 2;         // 1600000
    const int nbuck = (N + DPB - 1) / DPB;     // 782 (<= NBUCK_MAX)

    // Workspace (~59 MB). pairs aliases meanb: pairs dies at csr_build_kernel,
    // meanb is born at aggregate_kernel (strictly later on the same stream).
    char* ws = (char*)d_ws;
    size_t o = 0;
    auto alloc = [&](size_t bytes) { void* p = ws + o; o += (bytes + 255) & ~(size_t)255; return p; };
    int*            deg_i   = (int*)           alloc((size_t)N * 4);
    int*            start_i = (int*)           alloc((size_t)N * 4);
    int*            gcnt    = (int*)           alloc((size_t)nbuck * 4);
    int*            gbase   = (int*)           alloc((size_t)nbuck * 4);
    int*            csr     = (int*)           alloc((size_t)E * 4);
    unsigned short* xb      = (unsigned short*)alloc((size_t)N * NDIM * 2);  // doubles as hb
    unsigned short* meanb   = (unsigned short*)alloc((size_t)N * NDIM * 2);  // ∪ pairs
    unsigned short* wt1     = (unsigned short*)alloc(128 * 256 * 2);
    unsigned short* wt2     = (unsigned short*)alloc(128 * 256 * 2);
    unsigned int*   pairs   = (unsigned int*)meanb;   // 782*4096*4 = 12.8MB <= 25.6MB

    hipMemsetAsync(gcnt, 0, (size_t)nbuck * 4, stream);

    // Prep: bf16 cast + transposed bf16 weights
    int n4 = (N * NDIM) / 4;
    cast_bf16_kernel<<<(n4 + 255) / 256, 256, 0, stream>>>(x, xb, n4);
    build_wt_kernel<<<(128 * 256 + 255) / 256, 256, 0, stream>>>(
        W1_l, W1_r, W2_l, W2_r, wt1, wt2);

    // CSR build (binned, once; shared by both layers)
    int per = (E + NBIN - 1) / NBIN;
    bin_kernel<<<NBIN, 256, 0, stream>>>(ei, gcnt, pairs, E, nbuck, per);
    bucket_scan_kernel<<<1, 1024, 0, stream>>>(gcnt, gbase, nbuck);
    csr_build_kernel<<<nbuck, 256, 0, stream>>>(
        pairs, gcnt, gbase, csr, deg_i, start_i, N);

    int agg_blocks  = (N + 3) / 4;          // 4 nodes (waves) per 256-thr block
    int gemm_blocks = (N + 63) / 64;
    unsigned short* hb = xb;                 // layer-1 bf16 output aliases xb

    // ---- Layer 1 ----
    aggregate_kernel<<<agg_blocks, 256, 0, stream>>>(xb, csr, start_i, deg_i, meanb, N);
    sage_gemm_kernel<true, true><<<gemm_blocks, 256, 0, stream>>>(
        meanb, xb, wt1, b1_l, hb, N);

    // ---- Layer 2 ----
    aggregate_kernel<<<agg_blocks, 256, 0, stream>>>(hb, csr, start_i, deg_i, meanb, N);
    sage_gemm_kernel<false, false><<<gemm_blocks, 256, 0, stream>>>(
        meanb, hb, wt2, b2_l, out, N);
}